// Round 6
// baseline (526.005 us; speedup 1.0000x reference)
//
#include <hip/hip_runtime.h>
#include <hip/hip_bf16.h>

// MoE SwiGLU MLP, sparse top-2 path.
// T=2048 tokens, D_MODEL=1024, D_FF=2048, E=8 experts, K=2.
// R5: (a) k_prep_w rebuilt on global_load_lds: sequential 1KB DMA reads into
//     LDS (deep HW queue, no VGPR-bound MLP — R3/R4 strided reads stuck at
//     2.25 TB/s), rotated-row ds_read_b128 transpose, contiguous bf16 stores.
//     (b) k_combine fused into stage B epilogue via atomicAdd(y, w*(acc+bd))
//     with a per-slot weight table; outp buffer + kernel removed; y zeroed
//     by hipMemsetAsync.

#define D_MODEL 1024
#define D_FF    2048
#define N_EXP   8
#define T_TOK   2048
#define MAXTILES 40   // sum_e ceil(cnt_e/128) <= 32+7 < 40

typedef __attribute__((ext_vector_type(8))) short bf16x8;
typedef __attribute__((ext_vector_type(8))) ushort u16x8;
typedef __attribute__((ext_vector_type(4))) float f32x4;

__device__ __forceinline__ ushort f2bf(float f) {
    union { float f; unsigned u; } c; c.f = f;
    unsigned u = c.u;
    return (ushort)((u + 0x7fffu + ((u >> 16) & 1u)) >> 16);  // RTNE
}

__device__ __forceinline__ void glds16(const void* g, void* l) {
    __builtin_amdgcn_global_load_lds(
        (const __attribute__((address_space(1))) unsigned int*)g,
        (__attribute__((address_space(3))) unsigned int*)l, 16, 0, 0);
}

// ---------------- weight prep: fp32 -> bf16, tiled k-inner-8 16KB blocks ----------------
// Tile = 64 k x 128 n: [(kb*128 + ncol)*8 + ko], k = kb*8+ko.
// grid (256, 2): y=0: x>>7 -> Wg/Wu, e=(x>>4)&7, kt=x&15 (K=1024,N=2048)
//               y=1: Wd, e=x>>5, kt=x&31 (K=2048,N=1024)
// Per chunk: rows DMA'd to LDS row-major (sequential global reads), then
// rotated-row ds_read_b128 transpose -> contiguous bf16 stores.
__global__ __launch_bounds__(256) void k_prep_w(
    const float* __restrict__ Wg, const float* __restrict__ Wu, const float* __restrict__ Wd,
    ushort* __restrict__ Wgt, ushort* __restrict__ Wut, ushort* __restrict__ Wdt)
{
    __shared__ __align__(16) float lds[8224];   // max(4*2052, 8*1028) floats = 32.9 KB
    int tid = threadIdx.x, lane = tid & 63, w = tid >> 6;
    int x = blockIdx.x;

    if (blockIdx.y == 0) {
        // ---- Wg / Wu: 4-row chunks (ko half), S = 2052 floats ----
        int which = x >> 7;
        int e = (x >> 4) & 7, kt = x & 15;
        const float* src = (which ? Wu : Wg) + ((size_t)e * 1024 + kt * 64) * 2048;
        ushort* dst = which ? Wut : Wgt;
        const int S = 2052;
        int lp = ((lane & 3) << 4) | (lane >> 2);      // bank-decorrelating permute
        int n = (w * 64 + lp) * 8;                     // thread's n-octet, 0..2040
        int nt = n >> 7, nl = n & 127;
        ushort* dt = dst + (((size_t)(e * 16 + nt)) * 16 + kt) * 8192 + nl * 8;

        for (int c = 0; c < 16; c++) {
            __syncthreads();                           // LDS free from prev chunk
            const float* rp = src + (size_t)(c * 4 + w) * 2048;   // wave w -> row w
            float* lr = lds + w * S;
#pragma unroll
            for (int s = 0; s < 8; s++)
                glds16(rp + s * 256 + lane * 4, lr + s * 256 + lane * 4);
            __syncthreads();                           // drains vmcnt (DMA done)

            float4 v[4][2];
#pragma unroll
            for (int i = 0; i < 4; i++) {
                int r = ((lane & 3) + i) & 3;          // rotated rows: banks spread
                const float4* p = (const float4*)(lds + r * S + n);
                v[r][0] = p[0]; v[r][1] = p[1];
            }
            float el[4][8];
#pragma unroll
            for (int r = 0; r < 4; r++) {
                el[r][0] = v[r][0].x; el[r][1] = v[r][0].y; el[r][2] = v[r][0].z; el[r][3] = v[r][0].w;
                el[r][4] = v[r][1].x; el[r][5] = v[r][1].y; el[r][6] = v[r][1].z; el[r][7] = v[r][1].w;
            }
            int kb = c >> 1, koh = (c & 1) * 4;
            ushort* dd = dt + kb * 1024 + koh;
#pragma unroll
            for (int j = 0; j < 8; j++) {
                ushort4 o;
                o.x = f2bf(el[0][j]); o.y = f2bf(el[1][j]);
                o.z = f2bf(el[2][j]); o.w = f2bf(el[3][j]);
                *(ushort4*)(dd + j * 8) = o;
            }
        }
    } else {
        // ---- Wd: 8-row chunks (full kb), S = 1028 floats ----
        int e = x >> 5, kt = x & 31;
        const float* src = Wd + ((size_t)e * 2048 + kt * 64) * 1024;
        const int S = 1028;
        int lp = ((lane & 7) << 3) | (lane >> 3);
        int n = (w * 64 + lp) * 4;                     // thread's n-quad, 0..1020
        int nt = n >> 7, nl = n & 127;
        ushort* dt = Wdt + (((size_t)(e * 8 + nt)) * 32 + kt) * 8192 + nl * 8;

        for (int c = 0; c < 8; c++) {
            __syncthreads();
            const float* rp = src + (size_t)(c * 8 + w * 2) * 1024;  // wave w -> rows w*2, w*2+1
#pragma unroll
            for (int s = 0; s < 4; s++) {
                glds16(rp + s * 256 + lane * 4,        lds + (w * 2) * S + s * 256 + lane * 4);
                glds16(rp + 1024 + s * 256 + lane * 4, lds + (w * 2 + 1) * S + s * 256 + lane * 4);
            }
            __syncthreads();

            float4 v[8];
#pragma unroll
            for (int i = 0; i < 8; i++) {
                int r = ((lane & 7) + i) & 7;
                v[r] = *(const float4*)(lds + r * S + n);
            }
            ushort* dd = dt + c * 1024;
#pragma unroll
            for (int j = 0; j < 4; j++) {
                u16x8 o;
                o[0] = f2bf(j == 0 ? v[0].x : j == 1 ? v[0].y : j == 2 ? v[0].z : v[0].w);
                o[1] = f2bf(j == 0 ? v[1].x : j == 1 ? v[1].y : j == 2 ? v[1].z : v[1].w);
                o[2] = f2bf(j == 0 ? v[2].x : j == 1 ? v[2].y : j == 2 ? v[2].z : v[2].w);
                o[3] = f2bf(j == 0 ? v[3].x : j == 1 ? v[3].y : j == 2 ? v[3].z : v[3].w);
                o[4] = f2bf(j == 0 ? v[4].x : j == 1 ? v[4].y : j == 2 ? v[4].z : v[4].w);
                o[5] = f2bf(j == 0 ? v[5].x : j == 1 ? v[5].y : j == 2 ? v[5].z : v[5].w);
                o[6] = f2bf(j == 0 ? v[6].x : j == 1 ? v[6].y : j == 2 ? v[6].z : v[6].w);
                o[7] = f2bf(j == 0 ? v[7].x : j == 1 ? v[7].y : j == 2 ? v[7].z : v[7].w);
                *(u16x8*)(dd + j * 8) = o;
            }
        }
    }
}

// ---------------- router: 64 blocks x 32 tokens, block-aggregated atomics ----------------
// Emits xb (bf16 x) and wslot (per-slot combine weight for stage B).
__global__ __launch_bounds__(256) void k_router(
    const float* __restrict__ x, const float* __restrict__ gw, const float* __restrict__ gb,
    int* cnt, float* probsum, int* tok, float* wslot,
    ushort* __restrict__ xb)
{
    __shared__ float gws[N_EXP * D_MODEL];   // 32 KB
    __shared__ float ps_s[N_EXP];
    __shared__ int   bc_s[N_EXP];
    __shared__ int   gb_s[N_EXP];
    __shared__ int   a_e[64];
    __shared__ int   a_lp[64];
    __shared__ float a_w[64];

    int tid = threadIdx.x;
    for (int i = tid; i < N_EXP * D_MODEL / 4; i += 256)
        ((float4*)gws)[i] = ((const float4*)gw)[i];
    if (tid < N_EXP) { ps_s[tid] = 0.f; bc_s[tid] = 0; }
    __syncthreads();

    int wave = tid >> 6, lane = tid & 63;

    for (int it = 0; it < 8; it++) {
        int tb = it * 4 + wave;
        int t = blockIdx.x * 32 + tb;
        const float4* xr = (const float4*)(x + (size_t)t * D_MODEL);
        ushort* xbr = xb + (size_t)t * D_MODEL;

        float acc[N_EXP];
#pragma unroll
        for (int e = 0; e < N_EXP; e++) acc[e] = 0.f;
#pragma unroll
        for (int q = 0; q < 4; q++) {
            int idx = q * 64 + lane;
            float4 xv = xr[idx];
            ushort4 xc;
            xc.x = f2bf(xv.x); xc.y = f2bf(xv.y); xc.z = f2bf(xv.z); xc.w = f2bf(xv.w);
            *(ushort4*)&xbr[idx * 4] = xc;
#pragma unroll
            for (int e = 0; e < N_EXP; e++) {
                float4 gv = ((const float4*)(gws + e * D_MODEL))[idx];
                acc[e] += xv.x * gv.x + xv.y * gv.y + xv.z * gv.z + xv.w * gv.w;
            }
        }
#pragma unroll
        for (int off = 32; off > 0; off >>= 1) {
#pragma unroll
            for (int e = 0; e < N_EXP; e++) acc[e] += __shfl_xor(acc[e], off, 64);
        }
        if (lane == 0) {
            float l[N_EXP], m = -1e30f;
#pragma unroll
            for (int e = 0; e < N_EXP; e++) { l[e] = acc[e] + gb[e]; m = fmaxf(m, l[e]); }
            float p[N_EXP], s = 0.f;
#pragma unroll
            for (int e = 0; e < N_EXP; e++) { p[e] = expf(l[e] - m); s += p[e]; }
            float inv = 1.f / s;
#pragma unroll
            for (int e = 0; e < N_EXP; e++) { p[e] *= inv; atomicAdd(&ps_s[e], p[e]); }
            int i0 = 0; float v0 = p[0];
#pragma unroll
            for (int e = 1; e < N_EXP; e++) if (p[e] > v0) { v0 = p[e]; i0 = e; }
            int i1 = -1; float v1 = -1.f;
#pragma unroll
            for (int e = 0; e < N_EXP; e++) if (e != i0 && p[e] > v1) { v1 = p[e]; i1 = e; }
            float winv = 1.f / (v0 + v1);
            int lp0 = atomicAdd(&bc_s[i0], 1);
            int lp1 = atomicAdd(&bc_s[i1], 1);
            a_e[tb * 2 + 0] = i0; a_lp[tb * 2 + 0] = lp0; a_w[tb * 2 + 0] = v0 * winv;
            a_e[tb * 2 + 1] = i1; a_lp[tb * 2 + 1] = lp1; a_w[tb * 2 + 1] = v1 * winv;
        }
    }
    __syncthreads();
    if (tid < N_EXP) {
        gb_s[tid] = atomicAdd(&cnt[tid], bc_s[tid]);
        atomicAdd(&probsum[tid], ps_s[tid]);
    }
    __syncthreads();
    if (tid < 64) {
        int tb = tid >> 1;
        int t = blockIdx.x * 32 + tb;
        int e = a_e[tid];
        int slot = gb_s[e] + a_lp[tid];
        tok[e * T_TOK + slot] = t;
        wslot[e * T_TOK + slot] = a_w[tid];
    }
}

// ---------------- 128-aligned expert bases + tile table + balance loss ----------------
__global__ void k_base_loss(const int* __restrict__ cnt, const float* __restrict__ probsum,
                            int* abase, int* tile, float* loss_out)
{
    if (threadIdx.x == 0 && blockIdx.x == 0) {
        int b = 0, nt = 0;
        float loss = 0.f;
        for (int e = 0; e < N_EXP; e++) {
            abase[e] = b;
            for (int m0 = 0; m0 < cnt[e]; m0 += 128)
                tile[nt++] = (e << 16) | m0;
            b += ((cnt[e] + 127) >> 7) * 128;
            float mean = probsum[e] * (1.0f / T_TOK);
            loss += 0.125f * (logf(0.125f) - logf(mean + 1e-9f));
        }
        for (; nt < MAXTILES; nt++) tile[nt] = -1;
        *loss_out = loss;
    }
}

// ---------------- stage A: h = silu(x@Wg + bg) * (x@Wu + bu) ----------------
__global__ __launch_bounds__(256, 2) void k_expert_gu(
    const ushort* __restrict__ Wgt, const ushort* __restrict__ Wut,
    const float* __restrict__ bg, const float* __restrict__ bu,
    const ushort* __restrict__ xb, const int* __restrict__ cnt,
    const int* __restrict__ abase, const int* __restrict__ tile,
    const int* __restrict__ tok, ushort* __restrict__ h_t)
{
    int ti = tile[blockIdx.x];
    if (ti < 0) return;
    int e = ti >> 16, m0 = ti & 0xffff;
    int ne = cnt[e];
    int nt = blockIdx.y;
    int n0 = nt * 128;
    int stile = (abase[e] >> 7) + (m0 >> 7);

    __shared__ __align__(16) ushort As[128 * 88];
    __shared__ __align__(16) ushort Bg_s[8192];
    __shared__ __align__(16) ushort Bu_s[8192];

    int tid = threadIdx.x;
    int lane = tid & 63, wave = tid >> 6;
    int wm = (wave & 1) * 64, wn = (wave >> 1) * 64;

    int arow = tid >> 1;
    int akh = (tid & 1) * 32;
    int atok = tok[e * T_TOK + min(m0 + arow, ne - 1)];
    const ushort* xrow = xb + (size_t)atok * D_MODEL;

    const char* gbase = (const char*)(Wgt + (size_t)(e * 16 + nt) * 16 * 8192);
    const char* ubase = (const char*)(Wut + (size_t)(e * 16 + nt) * 16 * 8192);
    int goff = tid * 16;
    int loff = (tid >> 6) * 1024;

    f32x4 accg[4][4], accu[4][4];
#pragma unroll
    for (int i = 0; i < 4; i++)
#pragma unroll
        for (int j = 0; j < 4; j++) {
            accg[i][j] = (f32x4){0.f, 0.f, 0.f, 0.f};
            accu[i][j] = (f32x4){0.f, 0.f, 0.f, 0.f};
        }

    for (int kt = 0; kt < D_MODEL / 64; kt++) {
        __syncthreads();
#pragma unroll
        for (int q = 0; q < 4; q++)
            *(uint4*)&As[arow * 88 + akh + q * 8] = *(const uint4*)&xrow[kt * 64 + akh + q * 8];
        const char* gsrc = gbase + kt * 16384;
        const char* usrc = ubase + kt * 16384;
#pragma unroll
        for (int q = 0; q < 4; q++) {
            glds16(gsrc + q * 4096 + goff, (char*)Bg_s + q * 4096 + loff);
            glds16(usrc + q * 4096 + goff, (char*)Bu_s + q * 4096 + loff);
        }
        __syncthreads();
#pragma unroll
        for (int ks = 0; ks < 2; ks++) {
            bf16x8 af[4];
            int arow_f = wm + (lane & 15);
            int akb = ks * 32 + (lane >> 4) * 8;
#pragma unroll
            for (int sm = 0; sm < 4; sm++)
                af[sm] = *(const bf16x8*)&As[(arow_f + sm * 16) * 88 + akb];
            int bkb = ks * 4 + (lane >> 4);
#pragma unroll
            for (int sn = 0; sn < 4; sn++) {
                int ncol = wn + sn * 16 + (lane & 15);
                bf16x8 bgf = *(const bf16x8*)&Bg_s[(bkb * 128 + ncol) * 8];
                bf16x8 buf = *(const bf16x8*)&Bu_s[(bkb * 128 + ncol) * 8];
#pragma unroll
                for (int sm = 0; sm < 4; sm++) {
                    accg[sm][sn] = __builtin_amdgcn_mfma_f32_16x16x32_bf16(af[sm], bgf, accg[sm][sn], 0, 0, 0);
                    accu[sm][sn] = __builtin_amdgcn_mfma_f32_16x16x32_bf16(af[sm], buf, accu[sm][sn], 0, 0, 0);
                }
            }
        }
    }
    int rbase = wm + ((lane >> 4) << 2);
    int cbase = wn + (lane & 15);
    size_t tbase = (size_t)stile * 32 * 8192;
#pragma unroll
    for (int sm = 0; sm < 4; sm++) {
#pragma unroll
        for (int r = 0; r < 4; r++) {
            int pos = m0 + rbase + sm * 16 + r;
            if (pos < ne) {
                int row = pos & 127;
#pragma unroll
                for (int sn = 0; sn < 4; sn++) {
                    int col = n0 + cbase + sn * 16;
                    float g = accg[sm][sn][r] + bg[e * D_FF + col];
                    float u = accu[sm][sn][r] + bu[e * D_FF + col];
                    float hv = (g / (1.f + expf(-g))) * u;
                    int ktb = col >> 6, kb = (col >> 3) & 7, ko = col & 7;
                    h_t[tbase + (size_t)ktb * 8192 + (kb * 128 + row) * 8 + ko] = f2bf(hv);
                }
            }
        }
    }
}

// ---------------- stage B: y[tok[pos]] += w * (h @ Wd + bd)  (fused combine) ----------------
__global__ __launch_bounds__(256, 2) void k_expert_down(
    const ushort* __restrict__ Wdt, const float* __restrict__ bd,
    const ushort* __restrict__ h_t, const int* __restrict__ cnt,
    const int* __restrict__ abase, const int* __restrict__ tile,
    const int* __restrict__ tok, const float* __restrict__ wslot,
    float* __restrict__ y)
{
    int ti = tile[blockIdx.x];
    if (ti < 0) return;
    int e = ti >> 16, m0 = ti & 0xffff;
    int ne = cnt[e];
    int nt = blockIdx.y;
    int n0 = nt * 128;
    int stile = (abase[e] >> 7) + (m0 >> 7);

    __shared__ __align__(16) ushort As8[8192];
    __shared__ __align__(16) ushort Bd_s[8192];

    int tid = threadIdx.x;
    int lane = tid & 63, wave = tid >> 6;
    int wm = (wave & 1) * 64, wn = (wave >> 1) * 64;

    const char* hbase = (const char*)(h_t + (size_t)stile * 32 * 8192);
    const char* dbase = (const char*)(Wdt + (size_t)(e * 8 + nt) * 32 * 8192);
    int goff = tid * 16;
    int loff = (tid >> 6) * 1024;

    f32x4 acc[4][4];
#pragma unroll
    for (int i = 0; i < 4; i++)
#pragma unroll
        for (int j = 0; j < 4; j++) acc[i][j] = (f32x4){0.f, 0.f, 0.f, 0.f};

    for (int kt = 0; kt < D_FF / 64; kt++) {
        __syncthreads();
        const char* asrc = hbase + kt * 16384;
        const char* bsrc = dbase + kt * 16384;
#pragma unroll
        for (int q = 0; q < 4; q++) {
            glds16(asrc + q * 4096 + goff, (char*)As8 + q * 4096 + loff);
            glds16(bsrc + q * 4096 + goff, (char*)Bd_s + q * 4096 + loff);
        }
        __syncthreads();
#pragma unroll
        for (int ks = 0; ks < 2; ks++) {
            bf16x8 af[4];
            int kb = ks * 4 + (lane >> 4);
            int arow_f = wm + (lane & 15);
#pragma unroll
            for (int sm = 0; sm < 4; sm++)
                af[sm] = *(const bf16x8*)&As8[(kb * 128 + arow_f + sm * 16) * 8];
#pragma unroll
            for (int sn = 0; sn < 4; sn++) {
                int ncol = wn + sn * 16 + (lane & 15);
                bf16x8 bdf = *(const bf16x8*)&Bd_s[(kb * 128 + ncol) * 8];
#pragma unroll
                for (int sm = 0; sm < 4; sm++)
                    acc[sm][sn] = __builtin_amdgcn_mfma_f32_16x16x32_bf16(af[sm], bdf, acc[sm][sn], 0, 0, 0);
            }
        }
    }
    int rbase = wm + ((lane >> 4) << 2);
    int cbase = wn + (lane & 15);
#pragma unroll
    for (int sm = 0; sm < 4; sm++) {
#pragma unroll
        for (int r = 0; r < 4; r++) {
            int pos = m0 + rbase + sm * 16 + r;
            if (pos < ne) {
                int t = tok[e * T_TOK + pos];
                float wgt = wslot[e * T_TOK + pos];
                float* yrow = y + (size_t)t * D_MODEL;
#pragma unroll
                for (int sn = 0; sn < 4; sn++) {
                    int col = n0 + cbase + sn * 16;
                    atomicAdd(&yrow[col], wgt * (acc[sm][sn][r] + bd[e * D_MODEL + col]));
                }
            }
        }
    }
}

extern "C" void kernel_launch(void* const* d_in, const int* in_sizes, int n_in,
                              void* d_out, int out_size, void* d_ws, size_t ws_size,
                              hipStream_t stream)
{
    const float* x  = (const float*)d_in[0];
    const float* gw = (const float*)d_in[1];
    const float* gb = (const float*)d_in[2];
    const float* Wg = (const float*)d_in[3];
    const float* bg = (const float*)d_in[4];
    const float* Wu = (const float*)d_in[5];
    const float* bu = (const float*)d_in[6];
    const float* Wd = (const float*)d_in[7];
    const float* bd = (const float*)d_in[8];
    float* y = (float*)d_out;
    float* loss_out = y + (size_t)T_TOK * D_MODEL;

    char* ws = (char*)d_ws;
    int*    cnt     = (int*)(ws + 0);             // [zeroed, own line]
    float*  probsum = (float*)(ws + 128);         // [zeroed, own line]
    int*    abase   = (int*)(ws + 256);
    int*    tiletab = (int*)(ws + 320);
    float*  wslot   = (float*)(ws + 512);         // 8*2048 floats = 64 KB
    int*    tok     = (int*)(ws + 66048);         // 8*2048 ints = 64 KB
    ushort* xb      = (ushort*)(ws + 131072);     // 4 MB
    ushort* Wgt     = (ushort*)(ws + 4325376);    // 33.55 MB tiled bf16
    ushort* Wut     = (ushort*)(ws + 37879808);   // 33.55 MB
    ushort* Wdt     = (ushort*)(ws + 71434240);   // 33.55 MB
    ushort* h_t     = (ushort*)(ws + 104988672);  // 20.97 MB
    // total ws use: ~126 MB

    hipMemsetAsync(d_ws, 0, 256, stream);
    hipMemsetAsync(d_out, 0, (size_t)T_TOK * D_MODEL * sizeof(float), stream);
    k_prep_w<<<dim3(256, 2), dim3(256), 0, stream>>>(Wg, Wu, Wd, Wgt, Wut, Wdt);
    k_router<<<dim3(64), dim3(256), 0, stream>>>(x, gw, gb, cnt, probsum, tok, wslot, xb);
    k_base_loss<<<dim3(1), dim3(64), 0, stream>>>(cnt, probsum, abase, tiletab, loss_out);
    k_expert_gu<<<dim3(MAXTILES, 16), dim3(256), 0, stream>>>(Wgt, Wut, bg, bu, xb, cnt, abase, tiletab, tok, h_t);
    k_expert_down<<<dim3(MAXTILES, 8), dim3(256), 0, stream>>>(Wdt, bd, h_t, cnt, abase, tiletab, tok, wslot, y);
}

// Round 7
// 405.793 us; speedup vs baseline: 1.2962x; 1.2962x over previous
//
#include <hip/hip_runtime.h>
#include <hip/hip_bf16.h>

// MoE SwiGLU MLP, sparse top-2 path.
// T=2048 tokens, D_MODEL=1024, D_FF=2048, E=8 experts, K=2.
// R6: k_prep_w v3 — LDS-mediated transpose with BOTH global sides coalesced.
//     R5's failure: 8B-stride-16B stores + lane-permuted addresses => 411 MB
//     HBM write traffic (4x amplification). v3: stage1 = coalesced float4
//     reads -> bf16 row-major into LDS (lane-consecutive, conflict-free);
//     stage2 = per-n column of 8 ds_read_u16 (lane-consecutive n spans all 32
//     banks), pack u16x8, single 16B store, lane-consecutive => full sectors
//     written exactly once. 1024 blocks x 4 chunks, 32 KB LDS.

#define D_MODEL 1024
#define D_FF    2048
#define N_EXP   8
#define T_TOK   2048
#define MAXTILES 40   // sum_e ceil(cnt_e/128) <= 32+7 < 40

typedef __attribute__((ext_vector_type(8))) short bf16x8;
typedef __attribute__((ext_vector_type(8))) ushort u16x8;
typedef __attribute__((ext_vector_type(4))) float f32x4;

__device__ __forceinline__ ushort f2bf(float f) {
    union { float f; unsigned u; } c; c.f = f;
    unsigned u = c.u;
    return (ushort)((u + 0x7fffu + ((u >> 16) & 1u)) >> 16);  // RTNE
}

__device__ __forceinline__ void glds16(const void* g, void* l) {
    __builtin_amdgcn_global_load_lds(
        (const __attribute__((address_space(1))) unsigned int*)g,
        (__attribute__((address_space(3))) unsigned int*)l, 16, 0, 0);
}

// ---------------- weight prep: fp32 -> bf16, tiled k-inner-8 16KB blocks ----------------
// Tile = 64 k x 128 n: ushort offset (kb*128 + nl)*8 + ko, k = kb*8 + ko.
// Wg/Wu tiles: (e*16 + nt)*16 + kt (nt<16, kt<16). Wd tiles: (e*8 + nt)*32 + kt.
// grid 1024: x<512 -> Wg/Wu (which,e,kt,half); else Wd (e,kt,half). 4 chunks of
// 8 k-rows per block; per chunk: stage1 rows->LDS bf16, stage2 transpose-out.
__global__ __launch_bounds__(256) void k_prep_w(
    const float* __restrict__ Wg, const float* __restrict__ Wu, const float* __restrict__ Wd,
    ushort* __restrict__ Wgt, ushort* __restrict__ Wut, ushort* __restrict__ Wdt)
{
    __shared__ __align__(16) ushort lds[8 * 2048];   // 32 KB
    int tid = threadIdx.x;
    int x = blockIdx.x;

    if (x < 512) {
        // ---- Wg / Wu: N=2048 ----
        int which = x >> 8, e = (x >> 5) & 7, kt = (x >> 1) & 15, half = x & 1;
        const float* src = (which ? Wu : Wg) + ((size_t)e * 1024 + kt * 64) * 2048;
        ushort* dst = which ? Wut : Wgt;
        for (int c = half * 4; c < half * 4 + 4; c++) {
            __syncthreads();                               // LDS free from prev chunk
            const float4* s4 = (const float4*)(src + (size_t)c * 8 * 2048);
#pragma unroll
            for (int i = 0; i < 16; i++) {
                int f = i * 256 + tid;                     // 0..4095 float4s
                int j = f >> 9, col4 = f & 511;            // row 0..7, f4-col
                float4 v = s4[f];
                ushort4 o; o.x = f2bf(v.x); o.y = f2bf(v.y); o.z = f2bf(v.z); o.w = f2bf(v.w);
                *(ushort4*)&lds[j * 2048 + col4 * 4] = o;
            }
            __syncthreads();
#pragma unroll
            for (int p = 0; p < 8; p++) {
                int n = p * 256 + tid;
                u16x8 o;
#pragma unroll
                for (int j = 0; j < 8; j++) o[j] = lds[j * 2048 + n];
                int nt = n >> 7, nl = n & 127;
                *(u16x8*)(dst + (((size_t)(e * 16 + nt)) * 16 + kt) * 8192 + (c * 128 + nl) * 8) = o;
            }
        }
    } else {
        // ---- Wd: N=1024 ----
        int xx = x - 512;
        int e = (xx >> 6) & 7, kt = (xx >> 1) & 31, half = xx & 1;
        const float* src = Wd + ((size_t)e * 2048 + kt * 64) * 1024;
        for (int c = half * 4; c < half * 4 + 4; c++) {
            __syncthreads();
            const float4* s4 = (const float4*)(src + (size_t)c * 8 * 1024);
#pragma unroll
            for (int i = 0; i < 8; i++) {
                int f = i * 256 + tid;                     // 0..2047
                int j = f >> 8, col4 = f & 255;
                float4 v = s4[f];
                ushort4 o; o.x = f2bf(v.x); o.y = f2bf(v.y); o.z = f2bf(v.z); o.w = f2bf(v.w);
                *(ushort4*)&lds[j * 1024 + col4 * 4] = o;
            }
            __syncthreads();
#pragma unroll
            for (int p = 0; p < 4; p++) {
                int n = p * 256 + tid;
                u16x8 o;
#pragma unroll
                for (int j = 0; j < 8; j++) o[j] = lds[j * 1024 + n];
                int nt = n >> 7, nl = n & 127;
                *(u16x8*)(Wdt + (((size_t)(e * 8 + nt)) * 32 + kt) * 8192 + (c * 128 + nl) * 8) = o;
            }
        }
    }
}

// ---------------- router: 64 blocks x 32 tokens, block-aggregated atomics ----------------
// Emits xb (bf16 x) and wslot (per-slot combine weight for stage B).
__global__ __launch_bounds__(256) void k_router(
    const float* __restrict__ x, const float* __restrict__ gw, const float* __restrict__ gb,
    int* cnt, float* probsum, int* tok, float* wslot,
    ushort* __restrict__ xb)
{
    __shared__ float gws[N_EXP * D_MODEL];   // 32 KB
    __shared__ float ps_s[N_EXP];
    __shared__ int   bc_s[N_EXP];
    __shared__ int   gb_s[N_EXP];
    __shared__ int   a_e[64];
    __shared__ int   a_lp[64];
    __shared__ float a_w[64];

    int tid = threadIdx.x;
    for (int i = tid; i < N_EXP * D_MODEL / 4; i += 256)
        ((float4*)gws)[i] = ((const float4*)gw)[i];
    if (tid < N_EXP) { ps_s[tid] = 0.f; bc_s[tid] = 0; }
    __syncthreads();

    int wave = tid >> 6, lane = tid & 63;

    for (int it = 0; it < 8; it++) {
        int tb = it * 4 + wave;
        int t = blockIdx.x * 32 + tb;
        const float4* xr = (const float4*)(x + (size_t)t * D_MODEL);
        ushort* xbr = xb + (size_t)t * D_MODEL;

        float acc[N_EXP];
#pragma unroll
        for (int e = 0; e < N_EXP; e++) acc[e] = 0.f;
#pragma unroll
        for (int q = 0; q < 4; q++) {
            int idx = q * 64 + lane;
            float4 xv = xr[idx];
            ushort4 xc;
            xc.x = f2bf(xv.x); xc.y = f2bf(xv.y); xc.z = f2bf(xv.z); xc.w = f2bf(xv.w);
            *(ushort4*)&xbr[idx * 4] = xc;
#pragma unroll
            for (int e = 0; e < N_EXP; e++) {
                float4 gv = ((const float4*)(gws + e * D_MODEL))[idx];
                acc[e] += xv.x * gv.x + xv.y * gv.y + xv.z * gv.z + xv.w * gv.w;
            }
        }
#pragma unroll
        for (int off = 32; off > 0; off >>= 1) {
#pragma unroll
            for (int e = 0; e < N_EXP; e++) acc[e] += __shfl_xor(acc[e], off, 64);
        }
        if (lane == 0) {
            float l[N_EXP], m = -1e30f;
#pragma unroll
            for (int e = 0; e < N_EXP; e++) { l[e] = acc[e] + gb[e]; m = fmaxf(m, l[e]); }
            float p[N_EXP], s = 0.f;
#pragma unroll
            for (int e = 0; e < N_EXP; e++) { p[e] = expf(l[e] - m); s += p[e]; }
            float inv = 1.f / s;
#pragma unroll
            for (int e = 0; e < N_EXP; e++) { p[e] *= inv; atomicAdd(&ps_s[e], p[e]); }
            int i0 = 0; float v0 = p[0];
#pragma unroll
            for (int e = 1; e < N_EXP; e++) if (p[e] > v0) { v0 = p[e]; i0 = e; }
            int i1 = -1; float v1 = -1.f;
#pragma unroll
            for (int e = 0; e < N_EXP; e++) if (e != i0 && p[e] > v1) { v1 = p[e]; i1 = e; }
            float winv = 1.f / (v0 + v1);
            int lp0 = atomicAdd(&bc_s[i0], 1);
            int lp1 = atomicAdd(&bc_s[i1], 1);
            a_e[tb * 2 + 0] = i0; a_lp[tb * 2 + 0] = lp0; a_w[tb * 2 + 0] = v0 * winv;
            a_e[tb * 2 + 1] = i1; a_lp[tb * 2 + 1] = lp1; a_w[tb * 2 + 1] = v1 * winv;
        }
    }
    __syncthreads();
    if (tid < N_EXP) {
        gb_s[tid] = atomicAdd(&cnt[tid], bc_s[tid]);
        atomicAdd(&probsum[tid], ps_s[tid]);
    }
    __syncthreads();
    if (tid < 64) {
        int tb = tid >> 1;
        int t = blockIdx.x * 32 + tb;
        int e = a_e[tid];
        int slot = gb_s[e] + a_lp[tid];
        tok[e * T_TOK + slot] = t;
        wslot[e * T_TOK + slot] = a_w[tid];
    }
}

// ---------------- 128-aligned expert bases + tile table + balance loss ----------------
__global__ void k_base_loss(const int* __restrict__ cnt, const float* __restrict__ probsum,
                            int* abase, int* tile, float* loss_out)
{
    if (threadIdx.x == 0 && blockIdx.x == 0) {
        int b = 0, nt = 0;
        float loss = 0.f;
        for (int e = 0; e < N_EXP; e++) {
            abase[e] = b;
            for (int m0 = 0; m0 < cnt[e]; m0 += 128)
                tile[nt++] = (e << 16) | m0;
            b += ((cnt[e] + 127) >> 7) * 128;
            float mean = probsum[e] * (1.0f / T_TOK);
            loss += 0.125f * (logf(0.125f) - logf(mean + 1e-9f));
        }
        for (; nt < MAXTILES; nt++) tile[nt] = -1;
        *loss_out = loss;
    }
}

// ---------------- stage A: h = silu(x@Wg + bg) * (x@Wu + bu) ----------------
__global__ __launch_bounds__(256, 2) void k_expert_gu(
    const ushort* __restrict__ Wgt, const ushort* __restrict__ Wut,
    const float* __restrict__ bg, const float* __restrict__ bu,
    const ushort* __restrict__ xb, const int* __restrict__ cnt,
    const int* __restrict__ abase, const int* __restrict__ tile,
    const int* __restrict__ tok, ushort* __restrict__ h_t)
{
    int ti = tile[blockIdx.x];
    if (ti < 0) return;
    int e = ti >> 16, m0 = ti & 0xffff;
    int ne = cnt[e];
    int nt = blockIdx.y;
    int n0 = nt * 128;
    int stile = (abase[e] >> 7) + (m0 >> 7);

    __shared__ __align__(16) ushort As[128 * 88];
    __shared__ __align__(16) ushort Bg_s[8192];
    __shared__ __align__(16) ushort Bu_s[8192];

    int tid = threadIdx.x;
    int lane = tid & 63, wave = tid >> 6;
    int wm = (wave & 1) * 64, wn = (wave >> 1) * 64;

    int arow = tid >> 1;
    int akh = (tid & 1) * 32;
    int atok = tok[e * T_TOK + min(m0 + arow, ne - 1)];
    const ushort* xrow = xb + (size_t)atok * D_MODEL;

    const char* gbase = (const char*)(Wgt + (size_t)(e * 16 + nt) * 16 * 8192);
    const char* ubase = (const char*)(Wut + (size_t)(e * 16 + nt) * 16 * 8192);
    int goff = tid * 16;
    int loff = (tid >> 6) * 1024;

    f32x4 accg[4][4], accu[4][4];
#pragma unroll
    for (int i = 0; i < 4; i++)
#pragma unroll
        for (int j = 0; j < 4; j++) {
            accg[i][j] = (f32x4){0.f, 0.f, 0.f, 0.f};
            accu[i][j] = (f32x4){0.f, 0.f, 0.f, 0.f};
        }

    for (int kt = 0; kt < D_MODEL / 64; kt++) {
        __syncthreads();
#pragma unroll
        for (int q = 0; q < 4; q++)
            *(uint4*)&As[arow * 88 + akh + q * 8] = *(const uint4*)&xrow[kt * 64 + akh + q * 8];
        const char* gsrc = gbase + kt * 16384;
        const char* usrc = ubase + kt * 16384;
#pragma unroll
        for (int q = 0; q < 4; q++) {
            glds16(gsrc + q * 4096 + goff, (char*)Bg_s + q * 4096 + loff);
            glds16(usrc + q * 4096 + goff, (char*)Bu_s + q * 4096 + loff);
        }
        __syncthreads();
#pragma unroll
        for (int ks = 0; ks < 2; ks++) {
            bf16x8 af[4];
            int arow_f = wm + (lane & 15);
            int akb = ks * 32 + (lane >> 4) * 8;
#pragma unroll
            for (int sm = 0; sm < 4; sm++)
                af[sm] = *(const bf16x8*)&As[(arow_f + sm * 16) * 88 + akb];
            int bkb = ks * 4 + (lane >> 4);
#pragma unroll
            for (int sn = 0; sn < 4; sn++) {
                int ncol = wn + sn * 16 + (lane & 15);
                bf16x8 bgf = *(const bf16x8*)&Bg_s[(bkb * 128 + ncol) * 8];
                bf16x8 buf = *(const bf16x8*)&Bu_s[(bkb * 128 + ncol) * 8];
#pragma unroll
                for (int sm = 0; sm < 4; sm++) {
                    accg[sm][sn] = __builtin_amdgcn_mfma_f32_16x16x32_bf16(af[sm], bgf, accg[sm][sn], 0, 0, 0);
                    accu[sm][sn] = __builtin_amdgcn_mfma_f32_16x16x32_bf16(af[sm], buf, accu[sm][sn], 0, 0, 0);
                }
            }
        }
    }
    int rbase = wm + ((lane >> 4) << 2);
    int cbase = wn + (lane & 15);
    size_t tbase = (size_t)stile * 32 * 8192;
#pragma unroll
    for (int sm = 0; sm < 4; sm++) {
#pragma unroll
        for (int r = 0; r < 4; r++) {
            int pos = m0 + rbase + sm * 16 + r;
            if (pos < ne) {
                int row = pos & 127;
#pragma unroll
                for (int sn = 0; sn < 4; sn++) {
                    int col = n0 + cbase + sn * 16;
                    float g = accg[sm][sn][r] + bg[e * D_FF + col];
                    float u = accu[sm][sn][r] + bu[e * D_FF + col];
                    float hv = (g / (1.f + expf(-g))) * u;
                    int ktb = col >> 6, kb = (col >> 3) & 7, ko = col & 7;
                    h_t[tbase + (size_t)ktb * 8192 + (kb * 128 + row) * 8 + ko] = f2bf(hv);
                }
            }
        }
    }
}

// ---------------- stage B: y[tok[pos]] += w * (h @ Wd + bd)  (fused combine) ----------------
__global__ __launch_bounds__(256, 2) void k_expert_down(
    const ushort* __restrict__ Wdt, const float* __restrict__ bd,
    const ushort* __restrict__ h_t, const int* __restrict__ cnt,
    const int* __restrict__ abase, const int* __restrict__ tile,
    const int* __restrict__ tok, const float* __restrict__ wslot,
    float* __restrict__ y)
{
    int ti = tile[blockIdx.x];
    if (ti < 0) return;
    int e = ti >> 16, m0 = ti & 0xffff;
    int ne = cnt[e];
    int nt = blockIdx.y;
    int n0 = nt * 128;
    int stile = (abase[e] >> 7) + (m0 >> 7);

    __shared__ __align__(16) ushort As8[8192];
    __shared__ __align__(16) ushort Bd_s[8192];

    int tid = threadIdx.x;
    int lane = tid & 63, wave = tid >> 6;
    int wm = (wave & 1) * 64, wn = (wave >> 1) * 64;

    const char* hbase = (const char*)(h_t + (size_t)stile * 32 * 8192);
    const char* dbase = (const char*)(Wdt + (size_t)(e * 8 + nt) * 32 * 8192);
    int goff = tid * 16;
    int loff = (tid >> 6) * 1024;

    f32x4 acc[4][4];
#pragma unroll
    for (int i = 0; i < 4; i++)
#pragma unroll
        for (int j = 0; j < 4; j++) acc[i][j] = (f32x4){0.f, 0.f, 0.f, 0.f};

    for (int kt = 0; kt < D_FF / 64; kt++) {
        __syncthreads();
        const char* asrc = hbase + kt * 16384;
        const char* bsrc = dbase + kt * 16384;
#pragma unroll
        for (int q = 0; q < 4; q++) {
            glds16(asrc + q * 4096 + goff, (char*)As8 + q * 4096 + loff);
            glds16(bsrc + q * 4096 + goff, (char*)Bd_s + q * 4096 + loff);
        }
        __syncthreads();
#pragma unroll
        for (int ks = 0; ks < 2; ks++) {
            bf16x8 af[4];
            int kb = ks * 4 + (lane >> 4);
            int arow_f = wm + (lane & 15);
#pragma unroll
            for (int sm = 0; sm < 4; sm++)
                af[sm] = *(const bf16x8*)&As8[(kb * 128 + arow_f + sm * 16) * 8];
#pragma unroll
            for (int sn = 0; sn < 4; sn++) {
                int ncol = wn + sn * 16 + (lane & 15);
                bf16x8 bdf = *(const bf16x8*)&Bd_s[(kb * 128 + ncol) * 8];
#pragma unroll
                for (int sm = 0; sm < 4; sm++)
                    acc[sm][sn] = __builtin_amdgcn_mfma_f32_16x16x32_bf16(af[sm], bdf, acc[sm][sn], 0, 0, 0);
            }
        }
    }
    int rbase = wm + ((lane >> 4) << 2);
    int cbase = wn + (lane & 15);
#pragma unroll
    for (int sm = 0; sm < 4; sm++) {
#pragma unroll
        for (int r = 0; r < 4; r++) {
            int pos = m0 + rbase + sm * 16 + r;
            if (pos < ne) {
                int t = tok[e * T_TOK + pos];
                float wgt = wslot[e * T_TOK + pos];
                float* yrow = y + (size_t)t * D_MODEL;
#pragma unroll
                for (int sn = 0; sn < 4; sn++) {
                    int col = n0 + cbase + sn * 16;
                    atomicAdd(&yrow[col], wgt * (acc[sm][sn][r] + bd[e * D_MODEL + col]));
                }
            }
        }
    }
}

extern "C" void kernel_launch(void* const* d_in, const int* in_sizes, int n_in,
                              void* d_out, int out_size, void* d_ws, size_t ws_size,
                              hipStream_t stream)
{
    const float* x  = (const float*)d_in[0];
    const float* gw = (const float*)d_in[1];
    const float* gb = (const float*)d_in[2];
    const float* Wg = (const float*)d_in[3];
    const float* bg = (const float*)d_in[4];
    const float* Wu = (const float*)d_in[5];
    const float* bu = (const float*)d_in[6];
    const float* Wd = (const float*)d_in[7];
    const float* bd = (const float*)d_in[8];
    float* y = (float*)d_out;
    float* loss_out = y + (size_t)T_TOK * D_MODEL;

    char* ws = (char*)d_ws;
    int*    cnt     = (int*)(ws + 0);             // [zeroed, own line]
    float*  probsum = (float*)(ws + 128);         // [zeroed, own line]
    int*    abase   = (int*)(ws + 256);
    int*    tiletab = (int*)(ws + 320);
    float*  wslot   = (float*)(ws + 512);         // 8*2048 floats = 64 KB
    int*    tok     = (int*)(ws + 66048);         // 8*2048 ints = 64 KB
    ushort* xb      = (ushort*)(ws + 131072);     // 4 MB
    ushort* Wgt     = (ushort*)(ws + 4325376);    // 33.55 MB tiled bf16
    ushort* Wut     = (ushort*)(ws + 37879808);   // 33.55 MB
    ushort* Wdt     = (ushort*)(ws + 71434240);   // 33.55 MB
    ushort* h_t     = (ushort*)(ws + 104988672);  // 20.97 MB
    // total ws use: ~126 MB

    hipMemsetAsync(d_ws, 0, 256, stream);
    hipMemsetAsync(d_out, 0, (size_t)T_TOK * D_MODEL * sizeof(float), stream);
    k_prep_w<<<dim3(1024), dim3(256), 0, stream>>>(Wg, Wu, Wd, Wgt, Wut, Wdt);
    k_router<<<dim3(64), dim3(256), 0, stream>>>(x, gw, gb, cnt, probsum, tok, wslot, xb);
    k_base_loss<<<dim3(1), dim3(64), 0, stream>>>(cnt, probsum, abase, tiletab, loss_out);
    k_expert_gu<<<dim3(MAXTILES, 16), dim3(256), 0, stream>>>(Wgt, Wut, bg, bu, xb, cnt, abase, tiletab, tok, h_t);
    k_expert_down<<<dim3(MAXTILES, 8), dim3(256), 0, stream>>>(Wdt, bd, h_t, cnt, abase, tiletab, tok, wslot, y);
}